// Round 14
// baseline (452.236 us; speedup 1.0000x reference)
//
#include <hip/hip_runtime.h>
#include <math.h>

typedef unsigned int  u32;
typedef unsigned short u16;

#define TILE1 8192      // edges per pass-1 block (16/thread @ 512 threads)
#define BKW   256       // nodes per bucket (shift 8)
#define CAP   9216      // tmp slots per bucket (mean 8192, +11 sigma)

typedef __attribute__((ext_vector_type(8))) short bf16x8;
typedef __attribute__((ext_vector_type(4))) float f32x4;
union frag_u { bf16x8 v; u32 u[4]; uint4 q; };

__device__ inline u32 bf16_rne(float f) {
    u32 u = __float_as_uint(f);
    return (u + 0x7FFFu + ((u >> 16) & 1u)) >> 16;
}
__device__ inline float bf_lo(u32 u) { return __uint_as_float(u << 16); }
__device__ inline float bf_hi(u32 u) { return __uint_as_float(u & 0xFFFF0000u); }

__device__ inline void add8(float* acc, uint4 q) {
    acc[0] += bf_lo(q.x); acc[1] += bf_hi(q.x);
    acc[2] += bf_lo(q.y); acc[3] += bf_hi(q.y);
    acc[4] += bf_lo(q.z); acc[5] += bf_hi(q.z);
    acc[6] += bf_lo(q.w); acc[7] += bf_hi(q.w);
}

// relu on packed bf16x2: clear halves whose sign bit is set
__device__ inline u32 relu_pk(u32 v) {
    u32 s = v & 0x80008000u;
    u32 m = (s >> 15) * 0xFFFFu;
    return v & ~m;
}

// ================= CSR build: 2-pass radix partition =================

__global__ __launch_bounds__(512) void k_part1(const int* __restrict__ ei,
                                               int* __restrict__ bucketCur,
                                               u32* __restrict__ tmp,
                                               int E, int N, int NBK) {
    __shared__ int hist[1024];    // two replicas for count; [0:512) reused as cursor
    __shared__ int base[512];
    const int tid = threadIdx.x;
    if (tid < NBK) { hist[tid] = 0; hist[512 + tid] = 0; }
    __syncthreads();

    const int rep = (tid & 1) << 9;
    const int t0 = blockIdx.x * TILE1;
    const int4* ei4s = (const int4*)ei;             // E % 4 == 0
    const int4* ei4d = (const int4*)(ei + E);
    const int q0 = t0 >> 2;
    const int QE = E >> 2;

    int sv[16], dv[16], key[16];
#pragma unroll
    for (int j = 0; j < 4; ++j) {
        int qi = q0 + j * 512 + tid;
        int4 s4 = make_int4(0, 0, 0, 0), d4 = make_int4(-1, -1, -1, -1);
        if (qi < QE) { s4 = ei4s[qi]; d4 = ei4d[qi]; }
        sv[4 * j + 0] = s4.x; dv[4 * j + 0] = d4.x;
        sv[4 * j + 1] = s4.y; dv[4 * j + 1] = d4.y;
        sv[4 * j + 2] = s4.z; dv[4 * j + 2] = d4.z;
        sv[4 * j + 3] = s4.w; dv[4 * j + 3] = d4.w;
    }
#pragma unroll
    for (int j = 0; j < 16; ++j) {
        key[j] = -1;
        if ((unsigned)dv[j] < (unsigned)N && (unsigned)sv[j] < (unsigned)N) {
            key[j] = dv[j] >> 8;
            atomicAdd(&hist[key[j] + rep], 1);
        }
    }
    __syncthreads();
    if (tid < NBK) {
        int tot = hist[tid] + hist[512 + tid];
        base[tid] = atomicAdd(&bucketCur[tid], tot);
        hist[tid] = 0;                 // running cursor for placement
    }
    __syncthreads();
#pragma unroll
    for (int j = 0; j < 16; ++j) {
        if (key[j] >= 0) {
            int slot = atomicAdd(&hist[key[j]], 1);
            int off = base[key[j]] + slot;
            if (off < CAP)
                tmp[(size_t)key[j] * CAP + off] =
                    ((u32)(dv[j] & 255) << 17) | (u32)sv[j];
        }
    }
}

__global__ __launch_bounds__(512) void k_part2(const int* __restrict__ bucketCnt,
                                               const u32* __restrict__ tmp,
                                               int* __restrict__ csr,
                                               int* __restrict__ rowptr,
                                               float* __restrict__ dis,
                                               int N, int NBK) {
    __shared__ int hist[256];
    __shared__ int ts[512];
    __shared__ int sStart;
    const int b = blockIdx.x;
    const int t = threadIdx.x;

    int myCnt = (t < NBK) ? bucketCnt[t] : 0;
    ts[t] = myCnt;
    __syncthreads();
    for (int off = 1; off < 512; off <<= 1) {
        int u = (t >= off) ? ts[t - off] : 0;
        __syncthreads();
        ts[t] += u;
        __syncthreads();
    }
    if (t == b) sStart = ts[t] - myCnt;
    if (b == 0 && t == NBK - 1) rowptr[N] = ts[t];
    __syncthreads();
    const int start = sStart;
    const int cnt = bucketCnt[b];
    const u32* src = tmp + (size_t)b * CAP;

    if (t < 256) hist[t] = 0;
    __syncthreads();
    for (int i = t; i < cnt; i += 512)
        atomicAdd(&hist[src[i] >> 17], 1);
    __syncthreads();

    int h = (t < 256) ? hist[t] : 0;
    ts[t] = h;
    __syncthreads();
    for (int off = 1; off < 512; off <<= 1) {
        int u = (t >= off) ? ts[t - off] : 0;
        __syncthreads();
        ts[t] += u;
        __syncthreads();
    }
    if (t < 256) hist[t] = ts[t] - h;       // exclusive
    __syncthreads();

    if (t < 256) {
        int gn = (b << 8) + t;
        if (gn < N) {
            int e0 = hist[t];
            int e1 = (t < 255) ? hist[t + 1] : cnt;
            rowptr[gn] = start + e0;
            dis[gn] = rsqrtf((float)(e1 - e0) + 1.0f);
        }
    }
    __syncthreads();

    for (int i = t; i < cnt; i += 512) {
        u32 v = src[i];
        int p = atomicAdd(&hist[v >> 17], 1);
        csr[start + p] = (int)(v & 0x1FFFFu);
    }
}

// ========== weight convert (+ bucketCur zero): n-major bf16 hi/lo tables ==========

__global__ __launch_bounds__(256) void k_convW(
    const float* __restrict__ W1, const float* __restrict__ W2,
    u32* __restrict__ W1h, u32* __restrict__ W1l,
    u32* __restrict__ W2h, u32* __restrict__ W2l,
    int* __restrict__ bucketCur, int NBK)
{
    int idx = blockIdx.x * 256 + threadIdx.x;
    if (idx < NBK) bucketCur[idx] = 0;
    if (idx < 8192) {
        int n = idx >> 6, k = (idx & 63) * 2;
        float w0 = W1[k * 128 + n], w1 = W1[(k + 1) * 128 + n];
        u32 h0 = bf16_rne(w0), h1 = bf16_rne(w1);
        u32 l0 = bf16_rne(w0 - __uint_as_float(h0 << 16));
        u32 l1 = bf16_rne(w1 - __uint_as_float(h1 << 16));
        W1h[idx] = h0 | (h1 << 16);
        W1l[idx] = l0 | (l1 << 16);
    } else if (idx < 12288) {
        int i2 = idx - 8192;
        int n = i2 >> 6, k = (i2 & 63) * 2;
        float w0 = W2[k * 64 + n], w1 = W2[(k + 1) * 64 + n];
        u32 h0 = bf16_rne(w0), h1 = bf16_rne(w1);
        u32 l0 = bf16_rne(w0 - __uint_as_float(h0 << 16));
        u32 l1 = bf16_rne(w1 - __uint_as_float(h1 << 16));
        W2h[i2] = h0 | (h1 << 16);
        W2l[i2] = l0 | (l1 << 16);
    }
}

// ========== GEMM1 (MFMA): Hb1 = bf16( (X @ W1) * dis ), X fp32 hi/lo split ==========

__global__ __launch_bounds__(256) void k_gemm1m(
    const float* __restrict__ X, const u32* __restrict__ Wh,
    const u32* __restrict__ Wl, const float* __restrict__ dis,
    u32* __restrict__ Hb, int M)
{
    const int w = threadIdx.x >> 6, lane = threadIdx.x & 63;
    const int mrow = blockIdx.x * 64 + w * 16;
    if (mrow >= M) return;
    const int m16 = lane & 15, quad = lane >> 4;
    int gm = mrow + m16; if (gm >= M) gm = M - 1;

    frag_u Ah[4], Al[4];
    const float* xr = X + (size_t)gm * 128;
#pragma unroll
    for (int kt = 0; kt < 4; ++kt) {
        int kb = kt * 32 + quad * 8;
        float4 xa = *(const float4*)(xr + kb);
        float4 xb = *(const float4*)(xr + kb + 4);
        float xe[8] = {xa.x, xa.y, xa.z, xa.w, xb.x, xb.y, xb.z, xb.w};
#pragma unroll
        for (int j = 0; j < 4; ++j) {
            u32 h0 = bf16_rne(xe[2 * j]),     h1 = bf16_rne(xe[2 * j + 1]);
            u32 l0 = bf16_rne(xe[2 * j]     - __uint_as_float(h0 << 16));
            u32 l1 = bf16_rne(xe[2 * j + 1] - __uint_as_float(h1 << 16));
            Ah[kt].u[j] = h0 | (h1 << 16);
            Al[kt].u[j] = l0 | (l1 << 16);
        }
    }

    float dv[4];
#pragma unroll
    for (int r = 0; r < 4; ++r) {
        int gR = mrow + quad * 4 + r;
        dv[r] = (gR < M) ? dis[gR] : 0.f;
    }

    const uint4* Wh4 = (const uint4*)Wh;
    const uint4* Wl4 = (const uint4*)Wl;
#pragma unroll
    for (int nt = 0; nt < 8; ++nt) {
        f32x4 acc = {0.f, 0.f, 0.f, 0.f};
        int nrow = nt * 16 + m16;
#pragma unroll
        for (int kt = 0; kt < 4; ++kt) {
            frag_u Bh, Bl;
            Bh.q = Wh4[nrow * 16 + kt * 4 + quad];
            Bl.q = Wl4[nrow * 16 + kt * 4 + quad];
            acc = __builtin_amdgcn_mfma_f32_16x16x32_bf16(Al[kt].v, Bh.v, acc, 0, 0, 0);
            acc = __builtin_amdgcn_mfma_f32_16x16x32_bf16(Ah[kt].v, Bl.v, acc, 0, 0, 0);
            acc = __builtin_amdgcn_mfma_f32_16x16x32_bf16(Ah[kt].v, Bh.v, acc, 0, 0, 0);
        }
#pragma unroll
        for (int r = 0; r < 4; ++r) {
            float vs = acc[r] * dv[r];
            float vo = __shfl_xor(vs, 1, 64);
            if ((m16 & 1) == 0) {
                int gR = mrow + quad * 4 + r;
                if (gR < M)
                    Hb[(size_t)gR * 64 + nt * 8 + (m16 >> 1)] =
                        bf16_rne(vs) | (bf16_rne(vo) << 16);
            }
        }
    }
}

// ========== GEMM2 (MFMA): Hb2 = bf16( (relu(agg1b) @ W2) * dis ) ==========

__global__ __launch_bounds__(256) void k_gemm2m(
    const u32* __restrict__ Xb, const u32* __restrict__ Wh,
    const u32* __restrict__ Wl, const float* __restrict__ dis,
    u32* __restrict__ Hb, int M)
{
    const int w = threadIdx.x >> 6, lane = threadIdx.x & 63;
    const int mrow = blockIdx.x * 64 + w * 16;
    if (mrow >= M) return;
    const int m16 = lane & 15, quad = lane >> 4;
    int gm = mrow + m16; if (gm >= M) gm = M - 1;

    const uint4* X4 = (const uint4*)Xb;
    frag_u A[4];
#pragma unroll
    for (int kt = 0; kt < 4; ++kt) {
        A[kt].q = X4[(size_t)gm * 16 + kt * 4 + quad];
#pragma unroll
        for (int j = 0; j < 4; ++j) A[kt].u[j] = relu_pk(A[kt].u[j]);
    }

    float dv[4];
#pragma unroll
    for (int r = 0; r < 4; ++r) {
        int gR = mrow + quad * 4 + r;
        dv[r] = (gR < M) ? dis[gR] : 0.f;
    }

    const uint4* Wh4 = (const uint4*)Wh;
    const uint4* Wl4 = (const uint4*)Wl;
#pragma unroll
    for (int nt = 0; nt < 4; ++nt) {
        f32x4 acc = {0.f, 0.f, 0.f, 0.f};
        int nrow = nt * 16 + m16;
#pragma unroll
        for (int kt = 0; kt < 4; ++kt) {
            frag_u Bh, Bl;
            Bh.q = Wh4[nrow * 16 + kt * 4 + quad];
            Bl.q = Wl4[nrow * 16 + kt * 4 + quad];
            acc = __builtin_amdgcn_mfma_f32_16x16x32_bf16(A[kt].v, Bl.v, acc, 0, 0, 0);
            acc = __builtin_amdgcn_mfma_f32_16x16x32_bf16(A[kt].v, Bh.v, acc, 0, 0, 0);
        }
#pragma unroll
        for (int r = 0; r < 4; ++r) {
            float vs = acc[r] * dv[r];
            float vo = __shfl_xor(vs, 1, 64);
            if ((m16 & 1) == 0) {
                int gR = mrow + quad * 4 + r;
                if (gR < M)
                    Hb[(size_t)gR * 32 + nt * 8 + (m16 >> 1)] =
                        bf16_rne(vs) | (bf16_rne(vo) << 16);
            }
        }
    }
}

// ====== Aggregate L1 half (64 cols): wave/node, 8 edges per wave-instr.
// PART selects cols [PART*64, PART*64+64). Row = 16 uint4; half = 8 uint4. ======

template <int PART>
__global__ __launch_bounds__(256) void k_agg1h(
    const int* __restrict__ rowptr, const int* __restrict__ csr,
    const float* __restrict__ dis, const uint4* __restrict__ Hb4,
    const float* __restrict__ bias, u32* __restrict__ AGGb, int N)
{
    int n = (blockIdx.x * 256 + threadIdx.x) >> 6;
    int lane = threadIdx.x & 63;
    int slot = lane >> 3;        // 0..7
    int li   = lane & 7;         // uint4 index within half-row
    if (n >= N) return;
    int e = rowptr[n];
    const int s1 = rowptr[n + 1];
    const float dn = dis[n];
    const int q = PART * 8 + li;       // uint4 index within full row

    float acc[8];
#pragma unroll
    for (int j = 0; j < 8; ++j) acc[j] = 0.f;

    for (; e + 16 <= s1; e += 16) {
        int i0 = csr[e + slot];
        int i1 = csr[e + 8 + slot];
        uint4 q0 = Hb4[(size_t)i0 * 16 + q];
        uint4 q1 = Hb4[(size_t)i1 * 16 + q];
        add8(acc, q0); add8(acc, q1);
    }
    for (; e + 8 <= s1; e += 8) {
        int i0 = csr[e + slot];
        uint4 q0 = Hb4[(size_t)i0 * 16 + q];
        add8(acc, q0);
    }
    {
        int rem = s1 - e;
        int idx = -1;
        if (slot < rem) idx = csr[e + slot];
        else if (slot == rem) idx = n;          // self-loop row
        if (idx >= 0) {
            uint4 qq = Hb4[(size_t)idx * 16 + q];
            add8(acc, qq);
        }
    }

#pragma unroll
    for (int j = 0; j < 8; ++j) {
        acc[j] += __shfl_xor(acc[j], 8, 64);
        acc[j] += __shfl_xor(acc[j], 16, 64);
        acc[j] += __shfl_xor(acc[j], 32, 64);
    }

    // slot s<2 holds cols [8q+4s, 8q+4s+4) -> uint2 index 2q+s
    if (slot < 2) {
        float4 bv = ((const float4*)bias)[q * 2 + slot];
        float o0 = fmaf(dn, acc[4 * slot + 0], bv.x);
        float o1 = fmaf(dn, acc[4 * slot + 1], bv.y);
        float o2 = fmaf(dn, acc[4 * slot + 2], bv.z);
        float o3 = fmaf(dn, acc[4 * slot + 3], bv.w);
        uint2 p;
        p.x = bf16_rne(o0) | (bf16_rne(o1) << 16);
        p.y = bf16_rne(o2) | (bf16_rne(o3) << 16);
        ((uint2*)AGGb)[(size_t)n * 32 + q * 2 + slot] = p;
    }
}

// ====== Aggregate L2 (D=64): 8 edges per wave-instr; packed bf16 out ======

__global__ __launch_bounds__(256) void k_agg2(
    const int* __restrict__ rowptr, const int* __restrict__ csr,
    const float* __restrict__ dis, const uint4* __restrict__ Hb4,
    const float* __restrict__ bias, u32* __restrict__ AGGb, int N)
{
    int n = (blockIdx.x * 256 + threadIdx.x) >> 6;
    int lane = threadIdx.x & 63;
    int slot = lane >> 3;        // 0..7
    int li   = lane & 7;         // uint4 index within row (8 * 16B = 128B)
    if (n >= N) return;
    int e = rowptr[n];
    const int s1 = rowptr[n + 1];
    const float dn = dis[n];

    float acc[8];
#pragma unroll
    for (int j = 0; j < 8; ++j) acc[j] = 0.f;

    for (; e + 16 <= s1; e += 16) {
        int i0 = csr[e + slot];
        int i1 = csr[e + 8 + slot];
        uint4 q0 = Hb4[(size_t)i0 * 8 + li];
        uint4 q1 = Hb4[(size_t)i1 * 8 + li];
        add8(acc, q0); add8(acc, q1);
    }
    for (; e + 8 <= s1; e += 8) {
        int i0 = csr[e + slot];
        uint4 q0 = Hb4[(size_t)i0 * 8 + li];
        add8(acc, q0);
    }
    {
        int rem = s1 - e;
        int idx = -1;
        if (slot < rem) idx = csr[e + slot];
        else if (slot == rem) idx = n;
        if (idx >= 0) {
            uint4 q = Hb4[(size_t)idx * 8 + li];
            add8(acc, q);
        }
    }

#pragma unroll
    for (int j = 0; j < 8; ++j) {
        acc[j] += __shfl_xor(acc[j], 8, 64);
        acc[j] += __shfl_xor(acc[j], 16, 64);
        acc[j] += __shfl_xor(acc[j], 32, 64);
    }

    if (slot < 2) {
        float4 bv = ((const float4*)bias)[li * 2 + slot];
        float o0 = fmaf(dn, acc[4 * slot + 0], bv.x);
        float o1 = fmaf(dn, acc[4 * slot + 1], bv.y);
        float o2 = fmaf(dn, acc[4 * slot + 2], bv.z);
        float o3 = fmaf(dn, acc[4 * slot + 3], bv.w);
        uint2 p;
        p.x = bf16_rne(o0) | (bf16_rne(o1) << 16);
        p.y = bf16_rne(o2) | (bf16_rne(o3) << 16);
        ((uint2*)AGGb)[(size_t)n * 16 + li * 2 + slot] = p;
    }
}

// ========= mean pool over sorted batch (bf16 input) + fused classifier =========

__device__ inline int lower_bound(const int* __restrict__ b, int n, int v) {
    int lo = 0, hi = n;
    while (lo < hi) { int m = (lo + hi) >> 1; if (b[m] < v) lo = m + 1; else hi = m; }
    return lo;
}

__global__ __launch_bounds__(256) void k_poolfc(
    const int* __restrict__ batch, const u32* __restrict__ AGGb2,
    const float* __restrict__ Wfc, const float* __restrict__ bfc,
    float* __restrict__ out, int n)
{
    int g = blockIdx.x;
    int start = lower_bound(batch, n, g);
    int end   = lower_bound(batch, n, g + 1);
    int tid = threadIdx.x;
    int f = tid & 63, stripe = tid >> 6;
    int ui = f >> 1, hi = f & 1;
    float acc = 0.f;
    for (int i = start + stripe; i < end; i += 4) {
        u32 v = AGGb2[(size_t)i * 32 + ui];
        acc += hi ? bf_hi(v) : bf_lo(v);
    }
    __shared__ float red[256];
    __shared__ float mean[64];
    red[tid] = acc;
    __syncthreads();
    if (tid < 64) {
        float s = red[tid] + red[tid + 64] + red[tid + 128] + red[tid + 192];
        float c = (float)(end - start);
        mean[tid] = s / fmaxf(c, 1.0f);
    }
    __syncthreads();
    if (tid < 10) {
        float o = bfc[tid];
        for (int k = 0; k < 64; ++k)
            o = fmaf(mean[k], Wfc[k * 10 + tid], o);
        out[g * 10 + tid] = o;
    }
}

// ================= launch =================

extern "C" void kernel_launch(void* const* d_in, const int* in_sizes, int n_in,
                              void* d_out, int out_size, void* d_ws, size_t ws_size,
                              hipStream_t stream)
{
    const float* x    = (const float*)d_in[0];
    const int*   ei   = (const int*)d_in[1];
    const int*   batch= (const int*)d_in[2];
    const float* W1   = (const float*)d_in[3];
    const float* b1   = (const float*)d_in[4];
    const float* W2   = (const float*)d_in[5];
    const float* b2   = (const float*)d_in[6];
    const float* Wfc  = (const float*)d_in[7];
    const float* bfc  = (const float*)d_in[8];
    float* out = (float*)d_out;

    const int N  = in_sizes[0] / 128;     // 100000
    const int E  = in_sizes[1] / 2;       // 3200000
    const int ng = out_size / 10;         // 256

    const int NBK = (N + BKW - 1) / BKW;  // 391 buckets

    // ---- workspace layout (words) ----
    int*   rowptr    = (int*)d_ws;                          // 102400 (N+1)
    int*   bucketCur = rowptr + 102400;                     // 512
    float* dis       = (float*)(bucketCur + 512);           // 102400
    int*   csr       = (int*)(dis + 102400);                // E
    // region A (6.4M words): tmp (NBK*CAP=3.60M) -> Hb1 (N*64) -> agg2b (N*32)
    u32*   tmp       = (u32*)(csr + E);
    u32*   Hb1       = tmp;
    u32*   agg2b     = tmp;
    u32*   agg1b     = (u32*)((int*)tmp + (size_t)N * 64);      // N*64 u32 (bf16 packed)
    u16*   Hb2       = (u16*)((int*)agg1b + (size_t)N * 128);   // N*64 u16
    u32*   W1h       = (u32*)((int*)Hb2 + (size_t)N * 32);      // 8192
    u32*   W1l       = W1h + 8192;                              // 8192
    u32*   W2h       = W1l + 8192;                              // 4096
    u32*   W2l       = W2h + 4096;                              // 4096

    // ---- weight convert (+ bucketCur zero) + CSR build ----
    k_convW<<<48, 256, 0, stream>>>(W1, W2, W1h, W1l, W2h, W2l, bucketCur, NBK);
    k_part1<<<(E + TILE1 - 1) / TILE1, 512, 0, stream>>>(ei, bucketCur, tmp, E, N, NBK);
    k_part2<<<NBK, 512, 0, stream>>>(bucketCur, tmp, csr, rowptr, dis, N, NBK);

    // ---- layer 1 ----
    k_gemm1m<<<(N + 63) / 64, 256, 0, stream>>>(x, W1h, W1l, dis, Hb1, N);
    k_agg1h<0><<<(N + 3) / 4, 256, 0, stream>>>(rowptr, csr, dis, (const uint4*)Hb1, b1, agg1b, N);
    k_agg1h<1><<<(N + 3) / 4, 256, 0, stream>>>(rowptr, csr, dis, (const uint4*)Hb1, b1, agg1b, N);

    // ---- layer 2 ----
    k_gemm2m<<<(N + 63) / 64, 256, 0, stream>>>(agg1b, W2h, W2l, dis, (u32*)Hb2, N);
    k_agg2<<<(N + 3) / 4, 256, 0, stream>>>(rowptr, csr, dis, (const uint4*)Hb2, b2, agg2b, N);

    // ---- pool + classifier (fused) ----
    k_poolfc<<<ng, 256, 0, stream>>>(batch, agg2b, Wfc, bfc, out, N);
}

// Round 15
// 398.816 us; speedup vs baseline: 1.1339x; 1.1339x over previous
//
#include <hip/hip_runtime.h>
#include <math.h>

typedef unsigned int  u32;
typedef unsigned short u16;

#define TILE1 8192      // edges per pass-1 block (16/thread @ 512 threads)
#define BKW   256       // nodes per bucket (shift 8)
#define CAP   9216      // tmp slots per bucket (mean 8192, +11 sigma)

typedef __attribute__((ext_vector_type(8))) short bf16x8;
typedef __attribute__((ext_vector_type(4))) float f32x4;
union frag_u { bf16x8 v; u32 u[4]; uint4 q; };

__device__ inline u32 bf16_rne(float f) {
    u32 u = __float_as_uint(f);
    return (u + 0x7FFFu + ((u >> 16) & 1u)) >> 16;
}
__device__ inline float bf_lo(u32 u) { return __uint_as_float(u << 16); }
__device__ inline float bf_hi(u32 u) { return __uint_as_float(u & 0xFFFF0000u); }

__device__ inline void add8(float* acc, uint4 q) {
    acc[0] += bf_lo(q.x); acc[1] += bf_hi(q.x);
    acc[2] += bf_lo(q.y); acc[3] += bf_hi(q.y);
    acc[4] += bf_lo(q.z); acc[5] += bf_hi(q.z);
    acc[6] += bf_lo(q.w); acc[7] += bf_hi(q.w);
}

// relu on packed bf16x2: clear halves whose sign bit is set
__device__ inline u32 relu_pk(u32 v) {
    u32 s = v & 0x80008000u;
    u32 m = (s >> 15) * 0xFFFFu;
    return v & ~m;
}

// ================= CSR build: 2-pass radix partition =================

__global__ __launch_bounds__(512) void k_part1(const int* __restrict__ ei,
                                               int* __restrict__ bucketCur,
                                               u32* __restrict__ tmp,
                                               int E, int N, int NBK) {
    __shared__ int hist[1024];    // two replicas for count; [0:512) reused as cursor
    __shared__ int base[512];
    const int tid = threadIdx.x;
    if (tid < NBK) { hist[tid] = 0; hist[512 + tid] = 0; }
    __syncthreads();

    const int rep = (tid & 1) << 9;
    const int t0 = blockIdx.x * TILE1;
    const int4* ei4s = (const int4*)ei;             // E % 4 == 0
    const int4* ei4d = (const int4*)(ei + E);
    const int q0 = t0 >> 2;
    const int QE = E >> 2;

    int sv[16], dv[16], key[16];
#pragma unroll
    for (int j = 0; j < 4; ++j) {
        int qi = q0 + j * 512 + tid;
        int4 s4 = make_int4(0, 0, 0, 0), d4 = make_int4(-1, -1, -1, -1);
        if (qi < QE) { s4 = ei4s[qi]; d4 = ei4d[qi]; }
        sv[4 * j + 0] = s4.x; dv[4 * j + 0] = d4.x;
        sv[4 * j + 1] = s4.y; dv[4 * j + 1] = d4.y;
        sv[4 * j + 2] = s4.z; dv[4 * j + 2] = d4.z;
        sv[4 * j + 3] = s4.w; dv[4 * j + 3] = d4.w;
    }
#pragma unroll
    for (int j = 0; j < 16; ++j) {
        key[j] = -1;
        if ((unsigned)dv[j] < (unsigned)N && (unsigned)sv[j] < (unsigned)N) {
            key[j] = dv[j] >> 8;
            atomicAdd(&hist[key[j] + rep], 1);
        }
    }
    __syncthreads();
    if (tid < NBK) {
        int tot = hist[tid] + hist[512 + tid];
        base[tid] = atomicAdd(&bucketCur[tid], tot);
        hist[tid] = 0;                 // running cursor for placement
    }
    __syncthreads();
#pragma unroll
    for (int j = 0; j < 16; ++j) {
        if (key[j] >= 0) {
            int slot = atomicAdd(&hist[key[j]], 1);
            int off = base[key[j]] + slot;
            if (off < CAP)
                tmp[(size_t)key[j] * CAP + off] =
                    ((u32)(dv[j] & 255) << 17) | (u32)sv[j];
        }
    }
}

__global__ __launch_bounds__(512) void k_part2(const int* __restrict__ bucketCnt,
                                               const u32* __restrict__ tmp,
                                               int* __restrict__ csr,
                                               int* __restrict__ rowptr,
                                               float* __restrict__ dis,
                                               int N, int NBK) {
    __shared__ int hist[256];
    __shared__ int ts[512];
    __shared__ int sStart;
    const int b = blockIdx.x;
    const int t = threadIdx.x;

    int myCnt = (t < NBK) ? bucketCnt[t] : 0;
    ts[t] = myCnt;
    __syncthreads();
    for (int off = 1; off < 512; off <<= 1) {
        int u = (t >= off) ? ts[t - off] : 0;
        __syncthreads();
        ts[t] += u;
        __syncthreads();
    }
    if (t == b) sStart = ts[t] - myCnt;
    if (b == 0 && t == NBK - 1) rowptr[N] = ts[t];
    __syncthreads();
    const int start = sStart;
    const int cnt = bucketCnt[b];
    const u32* src = tmp + (size_t)b * CAP;

    if (t < 256) hist[t] = 0;
    __syncthreads();
    for (int i = t; i < cnt; i += 512)
        atomicAdd(&hist[src[i] >> 17], 1);
    __syncthreads();

    int h = (t < 256) ? hist[t] : 0;
    ts[t] = h;
    __syncthreads();
    for (int off = 1; off < 512; off <<= 1) {
        int u = (t >= off) ? ts[t - off] : 0;
        __syncthreads();
        ts[t] += u;
        __syncthreads();
    }
    if (t < 256) hist[t] = ts[t] - h;       // exclusive
    __syncthreads();

    if (t < 256) {
        int gn = (b << 8) + t;
        if (gn < N) {
            int e0 = hist[t];
            int e1 = (t < 255) ? hist[t + 1] : cnt;
            rowptr[gn] = start + e0;
            dis[gn] = rsqrtf((float)(e1 - e0) + 1.0f);
        }
    }
    __syncthreads();

    for (int i = t; i < cnt; i += 512) {
        u32 v = src[i];
        int p = atomicAdd(&hist[v >> 17], 1);
        csr[start + p] = (int)(v & 0x1FFFFu);
    }
}

// ========== weight convert (+ bucketCur zero): n-major bf16 hi/lo tables ==========

__global__ __launch_bounds__(256) void k_convW(
    const float* __restrict__ W1, const float* __restrict__ W2,
    u32* __restrict__ W1h, u32* __restrict__ W1l,
    u32* __restrict__ W2h, u32* __restrict__ W2l,
    int* __restrict__ bucketCur, int NBK)
{
    int idx = blockIdx.x * 256 + threadIdx.x;
    if (idx < NBK) bucketCur[idx] = 0;
    if (idx < 8192) {
        int n = idx >> 6, k = (idx & 63) * 2;
        float w0 = W1[k * 128 + n], w1 = W1[(k + 1) * 128 + n];
        u32 h0 = bf16_rne(w0), h1 = bf16_rne(w1);
        u32 l0 = bf16_rne(w0 - __uint_as_float(h0 << 16));
        u32 l1 = bf16_rne(w1 - __uint_as_float(h1 << 16));
        W1h[idx] = h0 | (h1 << 16);
        W1l[idx] = l0 | (l1 << 16);
    } else if (idx < 12288) {
        int i2 = idx - 8192;
        int n = i2 >> 6, k = (i2 & 63) * 2;
        float w0 = W2[k * 64 + n], w1 = W2[(k + 1) * 64 + n];
        u32 h0 = bf16_rne(w0), h1 = bf16_rne(w1);
        u32 l0 = bf16_rne(w0 - __uint_as_float(h0 << 16));
        u32 l1 = bf16_rne(w1 - __uint_as_float(h1 << 16));
        W2h[i2] = h0 | (h1 << 16);
        W2l[i2] = l0 | (l1 << 16);
    }
}

// ========== GEMM1 (MFMA, LDS-staged W): Hb1 = bf16( (X @ W1) * dis ) ==========
// Grid: (ceil(M/64), 2). blockIdx.y = n-half (cols [64*ny, 64*ny+64)).
// LDS: hi table 64 nrow x 17 uint4 (pad: 4-bank shift/nrow -> <=2-way, free),
//      lo table at +1088. 34816 B total.

__global__ __launch_bounds__(256) void k_gemm1m(
    const float* __restrict__ X, const u32* __restrict__ Wh,
    const u32* __restrict__ Wl, const float* __restrict__ dis,
    u32* __restrict__ Hb, int M)
{
    __shared__ uint4 sW[2176];
    const int tid = threadIdx.x;
    const int ny = blockIdx.y;
    const uint4* Wh4 = (const uint4*)Wh;
    const uint4* Wl4 = (const uint4*)Wl;
#pragma unroll
    for (int i = 0; i < 4; ++i) {
        int idx = tid + i * 256;
        int l = idx >> 4, j = idx & 15;
        sW[l * 17 + j] = Wh4[(ny * 64 + l) * 16 + j];
        sW[1088 + l * 17 + j] = Wl4[(ny * 64 + l) * 16 + j];
    }
    __syncthreads();

    const int w = tid >> 6, lane = tid & 63;
    const int mrow = blockIdx.x * 64 + w * 16;
    const int m16 = lane & 15, quad = lane >> 4;
    int gm = mrow + m16; if (gm >= M) gm = M - 1;

    frag_u Ah[4], Al[4];
    const float* xr = X + (size_t)gm * 128;
#pragma unroll
    for (int kt = 0; kt < 4; ++kt) {
        int kb = kt * 32 + quad * 8;
        float4 xa = *(const float4*)(xr + kb);
        float4 xb = *(const float4*)(xr + kb + 4);
        float xe[8] = {xa.x, xa.y, xa.z, xa.w, xb.x, xb.y, xb.z, xb.w};
#pragma unroll
        for (int j = 0; j < 4; ++j) {
            u32 h0 = bf16_rne(xe[2 * j]),     h1 = bf16_rne(xe[2 * j + 1]);
            u32 l0 = bf16_rne(xe[2 * j]     - __uint_as_float(h0 << 16));
            u32 l1 = bf16_rne(xe[2 * j + 1] - __uint_as_float(h1 << 16));
            Ah[kt].u[j] = h0 | (h1 << 16);
            Al[kt].u[j] = l0 | (l1 << 16);
        }
    }

    float dv[4];
#pragma unroll
    for (int r = 0; r < 4; ++r) {
        int gR = mrow + quad * 4 + r;
        dv[r] = (gR < M) ? dis[gR] : 0.f;
    }

#pragma unroll
    for (int nt = 0; nt < 4; ++nt) {
        f32x4 acc = {0.f, 0.f, 0.f, 0.f};
        int l = nt * 16 + m16;
#pragma unroll
        for (int kt = 0; kt < 4; ++kt) {
            frag_u Bh, Bl;
            Bh.q = sW[l * 17 + kt * 4 + quad];
            Bl.q = sW[1088 + l * 17 + kt * 4 + quad];
            acc = __builtin_amdgcn_mfma_f32_16x16x32_bf16(Al[kt].v, Bh.v, acc, 0, 0, 0);
            acc = __builtin_amdgcn_mfma_f32_16x16x32_bf16(Ah[kt].v, Bl.v, acc, 0, 0, 0);
            acc = __builtin_amdgcn_mfma_f32_16x16x32_bf16(Ah[kt].v, Bh.v, acc, 0, 0, 0);
        }
#pragma unroll
        for (int r = 0; r < 4; ++r) {
            float vs = acc[r] * dv[r];
            float vo = __shfl_xor(vs, 1, 64);
            if ((m16 & 1) == 0) {
                int gR = mrow + quad * 4 + r;
                if (gR < M)
                    Hb[(size_t)gR * 64 + ny * 32 + nt * 8 + (m16 >> 1)] =
                        bf16_rne(vs) | (bf16_rne(vo) << 16);
            }
        }
    }
}

// ========== GEMM2 (MFMA, LDS-staged W): Hb2 = bf16( (relu(agg1b) @ W2) * dis ) ==========

__global__ __launch_bounds__(256) void k_gemm2m(
    const u32* __restrict__ Xb, const u32* __restrict__ Wh,
    const u32* __restrict__ Wl, const float* __restrict__ dis,
    u32* __restrict__ Hb, int M)
{
    __shared__ uint4 sW[2176];
    const int tid = threadIdx.x;
    const uint4* Wh4 = (const uint4*)Wh;
    const uint4* Wl4 = (const uint4*)Wl;
#pragma unroll
    for (int i = 0; i < 4; ++i) {
        int idx = tid + i * 256;
        int l = idx >> 4, j = idx & 15;
        sW[l * 17 + j] = Wh4[l * 16 + j];
        sW[1088 + l * 17 + j] = Wl4[l * 16 + j];
    }
    __syncthreads();

    const int w = tid >> 6, lane = tid & 63;
    const int mrow = blockIdx.x * 64 + w * 16;
    const int m16 = lane & 15, quad = lane >> 4;
    int gm = mrow + m16; if (gm >= M) gm = M - 1;

    const uint4* X4 = (const uint4*)Xb;
    frag_u A[4];
#pragma unroll
    for (int kt = 0; kt < 4; ++kt) {
        A[kt].q = X4[(size_t)gm * 16 + kt * 4 + quad];
#pragma unroll
        for (int j = 0; j < 4; ++j) A[kt].u[j] = relu_pk(A[kt].u[j]);
    }

    float dv[4];
#pragma unroll
    for (int r = 0; r < 4; ++r) {
        int gR = mrow + quad * 4 + r;
        dv[r] = (gR < M) ? dis[gR] : 0.f;
    }

#pragma unroll
    for (int nt = 0; nt < 4; ++nt) {
        f32x4 acc = {0.f, 0.f, 0.f, 0.f};
        int l = nt * 16 + m16;
#pragma unroll
        for (int kt = 0; kt < 4; ++kt) {
            frag_u Bh, Bl;
            Bh.q = sW[l * 17 + kt * 4 + quad];
            Bl.q = sW[1088 + l * 17 + kt * 4 + quad];
            acc = __builtin_amdgcn_mfma_f32_16x16x32_bf16(A[kt].v, Bl.v, acc, 0, 0, 0);
            acc = __builtin_amdgcn_mfma_f32_16x16x32_bf16(A[kt].v, Bh.v, acc, 0, 0, 0);
        }
#pragma unroll
        for (int r = 0; r < 4; ++r) {
            float vs = acc[r] * dv[r];
            float vo = __shfl_xor(vs, 1, 64);
            if ((m16 & 1) == 0) {
                int gR = mrow + quad * 4 + r;
                if (gR < M)
                    Hb[(size_t)gR * 32 + nt * 8 + (m16 >> 1)] =
                        bf16_rne(vs) | (bf16_rne(vo) << 16);
            }
        }
    }
}

// ====== Aggregate L1 half (64 cols): wave/node, 8 edges per wave-instr ======

template <int PART>
__global__ __launch_bounds__(256) void k_agg1h(
    const int* __restrict__ rowptr, const int* __restrict__ csr,
    const float* __restrict__ dis, const uint4* __restrict__ Hb4,
    const float* __restrict__ bias, u32* __restrict__ AGGb, int N)
{
    int n = (blockIdx.x * 256 + threadIdx.x) >> 6;
    int lane = threadIdx.x & 63;
    int slot = lane >> 3;        // 0..7
    int li   = lane & 7;         // uint4 index within half-row
    if (n >= N) return;
    int e = rowptr[n];
    const int s1 = rowptr[n + 1];
    const float dn = dis[n];
    const int q = PART * 8 + li;       // uint4 index within full row

    float acc[8];
#pragma unroll
    for (int j = 0; j < 8; ++j) acc[j] = 0.f;

    for (; e + 16 <= s1; e += 16) {
        int i0 = csr[e + slot];
        int i1 = csr[e + 8 + slot];
        uint4 q0 = Hb4[(size_t)i0 * 16 + q];
        uint4 q1 = Hb4[(size_t)i1 * 16 + q];
        add8(acc, q0); add8(acc, q1);
    }
    for (; e + 8 <= s1; e += 8) {
        int i0 = csr[e + slot];
        uint4 q0 = Hb4[(size_t)i0 * 16 + q];
        add8(acc, q0);
    }
    {
        int rem = s1 - e;
        int idx = -1;
        if (slot < rem) idx = csr[e + slot];
        else if (slot == rem) idx = n;          // self-loop row
        if (idx >= 0) {
            uint4 qq = Hb4[(size_t)idx * 16 + q];
            add8(acc, qq);
        }
    }

#pragma unroll
    for (int j = 0; j < 8; ++j) {
        acc[j] += __shfl_xor(acc[j], 8, 64);
        acc[j] += __shfl_xor(acc[j], 16, 64);
        acc[j] += __shfl_xor(acc[j], 32, 64);
    }

    if (slot < 2) {
        float4 bv = ((const float4*)bias)[q * 2 + slot];
        float o0 = fmaf(dn, acc[4 * slot + 0], bv.x);
        float o1 = fmaf(dn, acc[4 * slot + 1], bv.y);
        float o2 = fmaf(dn, acc[4 * slot + 2], bv.z);
        float o3 = fmaf(dn, acc[4 * slot + 3], bv.w);
        uint2 p;
        p.x = bf16_rne(o0) | (bf16_rne(o1) << 16);
        p.y = bf16_rne(o2) | (bf16_rne(o3) << 16);
        ((uint2*)AGGb)[(size_t)n * 32 + q * 2 + slot] = p;
    }
}

// ====== Aggregate L2 (D=64): 8 edges per wave-instr; packed bf16 out ======

__global__ __launch_bounds__(256) void k_agg2(
    const int* __restrict__ rowptr, const int* __restrict__ csr,
    const float* __restrict__ dis, const uint4* __restrict__ Hb4,
    const float* __restrict__ bias, u32* __restrict__ AGGb, int N)
{
    int n = (blockIdx.x * 256 + threadIdx.x) >> 6;
    int lane = threadIdx.x & 63;
    int slot = lane >> 3;        // 0..7
    int li   = lane & 7;         // uint4 index within row (8 * 16B = 128B)
    if (n >= N) return;
    int e = rowptr[n];
    const int s1 = rowptr[n + 1];
    const float dn = dis[n];

    float acc[8];
#pragma unroll
    for (int j = 0; j < 8; ++j) acc[j] = 0.f;

    for (; e + 16 <= s1; e += 16) {
        int i0 = csr[e + slot];
        int i1 = csr[e + 8 + slot];
        uint4 q0 = Hb4[(size_t)i0 * 8 + li];
        uint4 q1 = Hb4[(size_t)i1 * 8 + li];
        add8(acc, q0); add8(acc, q1);
    }
    for (; e + 8 <= s1; e += 8) {
        int i0 = csr[e + slot];
        uint4 q0 = Hb4[(size_t)i0 * 8 + li];
        add8(acc, q0);
    }
    {
        int rem = s1 - e;
        int idx = -1;
        if (slot < rem) idx = csr[e + slot];
        else if (slot == rem) idx = n;
        if (idx >= 0) {
            uint4 q = Hb4[(size_t)idx * 8 + li];
            add8(acc, q);
        }
    }

#pragma unroll
    for (int j = 0; j < 8; ++j) {
        acc[j] += __shfl_xor(acc[j], 8, 64);
        acc[j] += __shfl_xor(acc[j], 16, 64);
        acc[j] += __shfl_xor(acc[j], 32, 64);
    }

    if (slot < 2) {
        float4 bv = ((const float4*)bias)[li * 2 + slot];
        float o0 = fmaf(dn, acc[4 * slot + 0], bv.x);
        float o1 = fmaf(dn, acc[4 * slot + 1], bv.y);
        float o2 = fmaf(dn, acc[4 * slot + 2], bv.z);
        float o3 = fmaf(dn, acc[4 * slot + 3], bv.w);
        uint2 p;
        p.x = bf16_rne(o0) | (bf16_rne(o1) << 16);
        p.y = bf16_rne(o2) | (bf16_rne(o3) << 16);
        ((uint2*)AGGb)[(size_t)n * 16 + li * 2 + slot] = p;
    }
}

// ========= mean pool over sorted batch (bf16 input) + fused classifier =========

__device__ inline int lower_bound(const int* __restrict__ b, int n, int v) {
    int lo = 0, hi = n;
    while (lo < hi) { int m = (lo + hi) >> 1; if (b[m] < v) lo = m + 1; else hi = m; }
    return lo;
}

__global__ __launch_bounds__(256) void k_poolfc(
    const int* __restrict__ batch, const u32* __restrict__ AGGb2,
    const float* __restrict__ Wfc, const float* __restrict__ bfc,
    float* __restrict__ out, int n)
{
    int g = blockIdx.x;
    int start = lower_bound(batch, n, g);
    int end   = lower_bound(batch, n, g + 1);
    int tid = threadIdx.x;
    int f = tid & 63, stripe = tid >> 6;
    int ui = f >> 1, hi = f & 1;
    float acc = 0.f;
    for (int i = start + stripe; i < end; i += 4) {
        u32 v = AGGb2[(size_t)i * 32 + ui];
        acc += hi ? bf_hi(v) : bf_lo(v);
    }
    __shared__ float red[256];
    __shared__ float mean[64];
    red[tid] = acc;
    __syncthreads();
    if (tid < 64) {
        float s = red[tid] + red[tid + 64] + red[tid + 128] + red[tid + 192];
        float c = (float)(end - start);
        mean[tid] = s / fmaxf(c, 1.0f);
    }
    __syncthreads();
    if (tid < 10) {
        float o = bfc[tid];
        for (int k = 0; k < 64; ++k)
            o = fmaf(mean[k], Wfc[k * 10 + tid], o);
        out[g * 10 + tid] = o;
    }
}

// ================= launch =================

extern "C" void kernel_launch(void* const* d_in, const int* in_sizes, int n_in,
                              void* d_out, int out_size, void* d_ws, size_t ws_size,
                              hipStream_t stream)
{
    const float* x    = (const float*)d_in[0];
    const int*   ei   = (const int*)d_in[1];
    const int*   batch= (const int*)d_in[2];
    const float* W1   = (const float*)d_in[3];
    const float* b1   = (const float*)d_in[4];
    const float* W2   = (const float*)d_in[5];
    const float* b2   = (const float*)d_in[6];
    const float* Wfc  = (const float*)d_in[7];
    const float* bfc  = (const float*)d_in[8];
    float* out = (float*)d_out;

    const int N  = in_sizes[0] / 128;     // 100000
    const int E  = in_sizes[1] / 2;       // 3200000
    const int ng = out_size / 10;         // 256

    const int NBK = (N + BKW - 1) / BKW;  // 391 buckets

    // ---- workspace layout (words) ----
    int*   rowptr    = (int*)d_ws;                          // 102400 (N+1)
    int*   bucketCur = rowptr + 102400;                     // 512
    float* dis       = (float*)(bucketCur + 512);           // 102400
    int*   csr       = (int*)(dis + 102400);                // E
    // region A (6.4M words): tmp (NBK*CAP=3.60M) -> Hb1 (N*64) -> agg2b (N*32)
    u32*   tmp       = (u32*)(csr + E);
    u32*   Hb1       = tmp;
    u32*   agg2b     = tmp;
    u32*   agg1b     = (u32*)((int*)tmp + (size_t)N * 64);      // N*64 u32 (bf16 packed)
    u16*   Hb2       = (u16*)((int*)agg1b + (size_t)N * 128);   // N*64 u16
    u32*   W1h       = (u32*)((int*)Hb2 + (size_t)N * 32);      // 8192
    u32*   W1l       = W1h + 8192;                              // 8192
    u32*   W2h       = W1l + 8192;                              // 4096
    u32*   W2l       = W2h + 4096;                              // 4096

    // ---- weight convert (+ bucketCur zero) + CSR build ----
    k_convW<<<48, 256, 0, stream>>>(W1, W2, W1h, W1l, W2h, W2l, bucketCur, NBK);
    k_part1<<<(E + TILE1 - 1) / TILE1, 512, 0, stream>>>(ei, bucketCur, tmp, E, N, NBK);
    k_part2<<<NBK, 512, 0, stream>>>(bucketCur, tmp, csr, rowptr, dis, N, NBK);

    // ---- layer 1 ----
    k_gemm1m<<<dim3((N + 63) / 64, 2), 256, 0, stream>>>(x, W1h, W1l, dis, Hb1, N);
    k_agg1h<0><<<(N + 3) / 4, 256, 0, stream>>>(rowptr, csr, dis, (const uint4*)Hb1, b1, agg1b, N);
    k_agg1h<1><<<(N + 3) / 4, 256, 0, stream>>>(rowptr, csr, dis, (const uint4*)Hb1, b1, agg1b, N);

    // ---- layer 2 ----
    k_gemm2m<<<(N + 63) / 64, 256, 0, stream>>>(agg1b, W2h, W2l, dis, (u32*)Hb2, N);
    k_agg2<<<(N + 3) / 4, 256, 0, stream>>>(rowptr, csr, dis, (const uint4*)Hb2, b2, agg2b, N);

    // ---- pool + classifier (fused) ----
    k_poolfc<<<ng, 256, 0, stream>>>(batch, agg2b, Wfc, bfc, out, N);
}